// Round 19
// baseline (51.498 us; speedup 1.0000x reference)
//
#include <hip/hip_runtime.h>
#include <hip/hip_bf16.h>
#include <math.h>
#include <limits.h>

// Problem constants (fixed by setup_inputs)
#define BS 2
#define NW 5
#define NS 5
#define NQ 5
#define FDIM 64
#define FH 21
#define FW 21
#define NPOS (FH*FW)            // 441
#define NIMG (BS*NW*(NS+NQ))    // 100
#define NQIMG 50
#define IMG_ELEMS (FDIM*NPOS)   // 28224
#define NY (NS*NPOS)            // 2205
#define QROWS 448               // 441 padded to 28*16
#define SROWS 2208              // 138 tiles of 16 rows; rows 2205..2207 zeroed
#define NSLICE 6                // y split: 138 = 6 * 23
#define NT_S 23                 // y-tiles per slice
#define NBLK 250
#define NBLK_SIM (NBLK*NSLICE)  // 1500
#define TILE_B 1024             // 16 rows x 64 B (i8) per tile

typedef __attribute__((ext_vector_type(4))) int int4v;

static __device__ __forceinline__ unsigned short f2bf(float x) {
    union { float f; unsigned u; } v; v.f = x;
    unsigned r = v.u + 0x7fffu + ((v.u >> 16) & 1u);
    return (unsigned short)(r >> 16);
}

static __device__ __forceinline__ float bf2f(unsigned short u) {
    union { unsigned u; float f; } v; v.u = ((unsigned)u) << 16;
    return v.f;
}

static __device__ __forceinline__ void gload_lds16(const void* g, void* l) {
    __builtin_amdgcn_global_load_lds((const __attribute__((address_space(1))) void*)g,
                                     (__attribute__((address_space(3))) void*)l, 16, 0, 0);
}

static __device__ __forceinline__ int med3i(int a, int b, int c) {
    int r;
    asm("v_med3_i32 %0, %1, %2, %3" : "=v"(r) : "v"(a), "v"(b), "v"(c));
    return r;
}

// r11-proven top-3 insert (ternary max): a0>=a1>=a2 sorted invariant
#define T3R(d, a0, a1, a2) do { \
    int _n0 = ((d) > (a0)) ? (d) : (a0); \
    int _n1 = med3i((d), (a0), (a1)); \
    int _n2 = med3i((d), (a1), (a2)); \
    (a0) = _n0; (a1) = _n1; (a2) = _n2; } while (0)

#define T3R4(p, s0, s1, s2, i) do { \
    T3R((p)[0], s0[i], s1[i], s2[i]); \
    T3R((p)[1], s0[i], s1[i], s2[i]); \
    T3R((p)[2], s0[i], s1[i], s2[i]); \
    T3R((p)[3], s0[i], s1[i], s2[i]); } while (0)

// float top-3 insert for the merge kernel
#define T3F(d, a0, a1, a2) do { \
    float _n0 = fmaxf((d), (a0)); \
    float _n1 = __builtin_amdgcn_fmed3f((d), (a0), (a1)); \
    float _n2 = __builtin_amdgcn_fmed3f((d), (a1), (a2)); \
    (a0) = _n0; (a1) = _n1; (a2) = _n2; } while (0)

// Kernel A: L2-normalize per (img,pos), quantize to i8 (scale 127, RNE).
__global__ __launch_bounds__(256) void dn4_normalize(const float* __restrict__ fm,
                                                     const int* __restrict__ elabel,
                                                     char* __restrict__ Qn,
                                                     char* __restrict__ Sn,
                                                     float* __restrict__ out) {
    int gid = blockIdx.x * blockDim.x + threadIdx.x;
    if (gid < 50) {   // label pass-through: out[250+gid]
        int bb = gid / 25, rem = gid % 25, wq = rem / 5, qi = rem % 5;
        out[250 + gid] = (float)elabel[(bb * NW + wq) * (NS + NQ) + NS + qi];
    }
    if (gid < 120) {  // zero S pad rows 2205..2207: 10 mats x 3 rows x 4 int4
        int mat = gid / 12, rr = (gid % 12) >> 2, k = gid & 3;
        int4v zv = {0, 0, 0, 0};
        *(int4v*)(Sn + (size_t)mat * (SROWS * FDIM) + (size_t)(NY + rr) * FDIM + k * 16) = zv;
    }
    if (gid >= NIMG * NPOS) return;
    int img = gid / NPOS;
    int pos = gid - img * NPOS;
    const float* src = fm + (size_t)img * IMG_ELEMS + pos;
    float v[FDIM];
    float ss = 0.f;
#pragma unroll
    for (int c = 0; c < FDIM; ++c) {
        float x = src[(size_t)c * NPOS];
        v[c] = x;
        ss += x * x;
    }
    float rn = 127.0f / (sqrtf(ss) + 1e-12f);
    int w[16];
#pragma unroll
    for (int k = 0; k < 16; ++k) {
        int q0 = __float2int_rn(v[4 * k]     * rn);
        int q1 = __float2int_rn(v[4 * k + 1] * rn);
        int q2 = __float2int_rn(v[4 * k + 2] * rn);
        int q3 = __float2int_rn(v[4 * k + 3] * rn);
        w[k] = (q0 & 0xff) | ((q1 & 0xff) << 8) | ((q2 & 0xff) << 16) | (q3 << 24);
    }
    char* dst;
    int i10 = img % 10;
    if (i10 < NS) {
        int bw = img / 10;
        dst = Sn + (size_t)bw * (SROWS * FDIM) + (size_t)(i10 * NPOS + pos) * FDIM;
    } else {
        int qidx = (img / 10) * NQ + (i10 - NS);
        dst = Qn + (size_t)qidx * (QROWS * FDIM) + (size_t)pos * FDIM;
    }
#pragma unroll
    for (int k = 0; k < 4; ++k) {
        int4v t = {w[4 * k], w[4 * k + 1], w[4 * k + 2], w[4 * k + 3]};
        *(int4v*)(dst + 16 * k) = t;
    }
}

// Kernel B: r16 dual-bank body + REGISTER DATAFLOW FENCE. After issuing the
// pair's 8 MFMAs, an empty asm takes all 8 results as "+v" operands: every
// producer must complete issue before the fence and every consumer reads the
// fence's outputs, so all 32 result-VGPRs are simultaneously live — the
// allocator cannot serialize issue->consume (r16/r17/r18 failure mode; r15
// measured ~26.5 µs for this body when the bank stayed live).
__global__ __launch_bounds__(448, 4) void dn4_sim_mfma(const char* __restrict__ Qn,
                                                       const char* __restrict__ Sn,
                                                       unsigned short* __restrict__ gtop3) {
    __shared__ __align__(16) char stile[NT_S][TILE_B];   // 23,552 B

    // m204 bijective chunked XCD swizzle over 1500 units (1500 = 8*187+4)
    int orig = blockIdx.x;
    int xcd = orig & 7, idx = orig >> 3;
    int unit = (xcd < 4 ? xcd * 188 : 4 * 188 + (xcd - 4) * 187) + idx;
    int bid = unit / NSLICE, ys = unit % NSLICE;

    int w = bid % NW;
    int q = (bid / NW) % (NW * NQ);
    int b = bid / (NW * NW * NQ);
    int wq = q / NQ, qi = q % NQ;
    int qidx = (b * NW + wq) * NQ + qi;

    const char* qbase = Qn + (size_t)qidx * (QROWS * FDIM);
    const char* sbase = Sn + (size_t)(b * NW + w) * (SROWS * FDIM);

    int t = threadIdx.x;
    int lane = t & 63, xg = t >> 6;
    int lo16 = lane & 15, hi4 = lane >> 4;

    // Stage source pre-swizzle: LDS linear [row][c] gets global [row][c ^ ((row>>1)&3)]
    int stg0 = ((lane >> 2) * FDIM) + ((((lane & 3) ^ ((lane >> 3) & 3)) << 4));
    int tbase = ys * NT_S;

    for (int i = xg; i < NT_S; i += 7)
        gload_lds16(sbase + (size_t)(tbase + i) * TILE_B + stg0, &stile[i][0]);

    // B fragments (Q): col = lo16 -> x = xt*16+lo16, k = hi4*16 .. +16
    int4v bq[4];
#pragma unroll
    for (int i = 0; i < 4; ++i) {
        int xt = xg * 4 + i;
        bq[i] = *(const int4v*)(qbase + (size_t)(xt * 16 + lo16) * FDIM + hi4 * 16);
    }

    asm volatile("s_waitcnt vmcnt(0)" ::: "memory");
    __syncthreads();   // the ONLY barrier

    int tA0[4], tA1[4], tA2[4], tB0[4], tB1[4], tB2[4];
#pragma unroll
    for (int i = 0; i < 4; ++i) {
        tA0[i] = INT_MIN; tA1[i] = INT_MIN; tA2[i] = INT_MIN;
        tB0[i] = INT_MIN; tB1[i] = INT_MIN; tB2[i] = INT_MIN;
    }

    int4v zc = {0, 0, 0, 0};

    // Swizzled read: row lo16, want col hi4 -> read hi4 ^ ((lo16>>1)&3)
    int rd = lo16 * FDIM + ((hi4 ^ ((lo16 >> 1) & 3)) << 4);

#define PROCPAIR(cA, cB) do { \
        int4v pA0 = __builtin_amdgcn_mfma_i32_16x16x64_i8((cA), bq[0], zc, 0, 0, 0); \
        int4v pB0 = __builtin_amdgcn_mfma_i32_16x16x64_i8((cB), bq[0], zc, 0, 0, 0); \
        int4v pA1 = __builtin_amdgcn_mfma_i32_16x16x64_i8((cA), bq[1], zc, 0, 0, 0); \
        int4v pB1 = __builtin_amdgcn_mfma_i32_16x16x64_i8((cB), bq[1], zc, 0, 0, 0); \
        int4v pA2 = __builtin_amdgcn_mfma_i32_16x16x64_i8((cA), bq[2], zc, 0, 0, 0); \
        int4v pB2 = __builtin_amdgcn_mfma_i32_16x16x64_i8((cB), bq[2], zc, 0, 0, 0); \
        int4v pA3 = __builtin_amdgcn_mfma_i32_16x16x64_i8((cA), bq[3], zc, 0, 0, 0); \
        int4v pB3 = __builtin_amdgcn_mfma_i32_16x16x64_i8((cB), bq[3], zc, 0, 0, 0); \
        /* dataflow fence: all 8 results live simultaneously */ \
        asm volatile("" : "+v"(pA0), "+v"(pB0), "+v"(pA1), "+v"(pB1), \
                          "+v"(pA2), "+v"(pB2), "+v"(pA3), "+v"(pB3)); \
        T3R4(pA0, tA0, tA1, tA2, 0); \
        T3R4(pB0, tB0, tB1, tB2, 0); \
        T3R4(pA1, tA0, tA1, tA2, 1); \
        T3R4(pB1, tB0, tB1, tB2, 1); \
        T3R4(pA2, tA0, tA1, tA2, 2); \
        T3R4(pB2, tB0, tB1, tB2, 2); \
        T3R4(pA3, tA0, tA1, tA2, 3); \
        T3R4(pB3, tB0, tB1, tB2, 3); } while (0)

    int4v caA = *(const int4v*)(&stile[0][0] + rd);
    int4v caB = *(const int4v*)(&stile[1][0] + rd);
    for (int k = 0; k < 10; ++k) {            // pairs (0,1)..(18,19)
        int4v naA = *(const int4v*)(&stile[2 * k + 2][0] + rd);
        int4v naB = *(const int4v*)(&stile[2 * k + 3][0] + rd);
        PROCPAIR(caA, caB);
        caA = naA; caB = naB;
    }
    {   // pair (20,21), prefetch 22 only (no out-of-range slot read)
        int4v naA = *(const int4v*)(&stile[22][0] + rd);
        PROCPAIR(caA, caB);
        caA = naA;
    }
    {   // tail tile 22 -> bank A (4 MFMAs, fenced the same way)
        int4v pA0 = __builtin_amdgcn_mfma_i32_16x16x64_i8(caA, bq[0], zc, 0, 0, 0);
        int4v pA1 = __builtin_amdgcn_mfma_i32_16x16x64_i8(caA, bq[1], zc, 0, 0, 0);
        int4v pA2 = __builtin_amdgcn_mfma_i32_16x16x64_i8(caA, bq[2], zc, 0, 0, 0);
        int4v pA3 = __builtin_amdgcn_mfma_i32_16x16x64_i8(caA, bq[3], zc, 0, 0, 0);
        asm volatile("" : "+v"(pA0), "+v"(pA1), "+v"(pA2), "+v"(pA3));
        T3R4(pA0, tA0, tA1, tA2, 0); T3R4(pA1, tA0, tA1, tA2, 1);
        T3R4(pA2, tA0, tA1, tA2, 2); T3R4(pA3, tA0, tA1, tA2, 3);
    }
#undef PROCPAIR

    // Merge bank B into A, then across the 4 y-quarter lane-groups; write bf16
    const float INV = 1.0f / 16129.0f;   // 1/127^2
#pragma unroll
    for (int i = 0; i < 4; ++i) {
        int a0 = tA0[i], a1 = tA1[i], a2 = tA2[i];
        T3R(tB0[i], a0, a1, a2);
        T3R(tB1[i], a0, a1, a2);
        T3R(tB2[i], a0, a1, a2);
#pragma unroll
        for (int mk = 16; mk <= 32; mk <<= 1) {
            int c0 = __shfl_xor(a0, mk, 64);
            int c1 = __shfl_xor(a1, mk, 64);
            int c2 = __shfl_xor(a2, mk, 64);
            T3R(c0, a0, a1, a2);
            T3R(c1, a0, a1, a2);
            T3R(c2, a0, a1, a2);
        }
        if (hi4 == 0) {
            int x = (xg * 4 + i) * 16 + lo16;
            unsigned short* dst = gtop3 + ((size_t)(bid * QROWS + x) * NSLICE + ys) * 3;
            dst[0] = f2bf((float)a0 * INV);
            dst[1] = f2bf((float)a1 * INV);
            dst[2] = f2bf((float)a2 * INV);
        }
    }
}

// Kernel C: merge the 6 y-slices per (bid,x), sum top-3, block-reduce -> out[bid]
__global__ __launch_bounds__(448) void dn4_merge(const unsigned short* __restrict__ gtop3,
                                                 float* __restrict__ out) {
    __shared__ float red[7];
    int bid = blockIdx.x;
    int t = threadIdx.x, lane = t & 63, wv = t >> 6;
    const unsigned* p = (const unsigned*)(gtop3 + (size_t)(bid * QROWS + t) * (NSLICE * 3));
    float v[18];
#pragma unroll
    for (int j = 0; j < 9; ++j) {
        unsigned u = p[j];
        v[2 * j]     = bf2f((unsigned short)(u & 0xffffu));
        v[2 * j + 1] = bf2f((unsigned short)(u >> 16));
    }
    float a0 = v[0], a1 = v[1], a2 = v[2];
#pragma unroll
    for (int j = 3; j < 18; ++j) T3F(v[j], a0, a1, a2);
    float s = (t < NPOS) ? (a0 + a1 + a2) : 0.f;
#pragma unroll
    for (int off = 32; off >= 1; off >>= 1) s += __shfl_xor(s, off, 64);
    if (lane == 0) red[wv] = s;
    __syncthreads();
    if (t == 0) {
        float tot = 0.f;
#pragma unroll
        for (int i = 0; i < 7; ++i) tot += red[i];
        out[bid] = tot;
    }
}

extern "C" void kernel_launch(void* const* d_in, const int* in_sizes, int n_in,
                              void* d_out, int out_size, void* d_ws, size_t ws_size,
                              hipStream_t stream) {
    const float* fm     = (const float*)d_in[0];
    const int*   elabel = (const int*)d_in[1];
    float* out = (float*)d_out;

    char* Qn = (char*)d_ws;                                   // 1.43 MB
    char* Sn = Qn + (size_t)NQIMG * QROWS * FDIM;             // 1.41 MB
    unsigned short* gtop3 = (unsigned short*)(Sn + (size_t)10 * SROWS * FDIM);  // 4.03 MB

    int nthreads = NIMG * NPOS;
    dn4_normalize<<<(nthreads + 255) / 256, 256, 0, stream>>>(fm, elabel, Qn, Sn, out);
    dn4_sim_mfma<<<NBLK_SIM, 448, 0, stream>>>(Qn, Sn, gtop3);
    dn4_merge<<<NBLK, 448, 0, stream>>>(gtop3, out);
}

// Round 20
// 50.351 us; speedup vs baseline: 1.0228x; 1.0228x over previous
//
#include <hip/hip_runtime.h>
#include <hip/hip_bf16.h>
#include <math.h>
#include <limits.h>

// Problem constants (fixed by setup_inputs)
#define BS 2
#define NW 5
#define NS 5
#define NQ 5
#define FDIM 64
#define FH 21
#define FW 21
#define NPOS (FH*FW)            // 441
#define NIMG (BS*NW*(NS+NQ))    // 100
#define NQIMG 50
#define IMG_ELEMS (FDIM*NPOS)   // 28224
#define NY (NS*NPOS)            // 2205
#define QROWS 448               // 441 padded to 28*16
#define SROWS 2304              // 144 tiles of 16 rows; rows 2205..2303 zeroed
#define NSLICE 12               // y split: 144 tiles = 12 * 12
#define NT_S 12                 // y-tiles per slice (12.3 KB LDS)
#define NBLK 250
#define NBLK_SIM (NBLK*NSLICE)  // 3000
#define TILE_B 1024             // 16 rows x 64 B (i8) per tile

typedef __attribute__((ext_vector_type(4))) int int4v;

static __device__ __forceinline__ unsigned short f2bf(float x) {
    union { float f; unsigned u; } v; v.f = x;
    unsigned r = v.u + 0x7fffu + ((v.u >> 16) & 1u);
    return (unsigned short)(r >> 16);
}

static __device__ __forceinline__ float bf2f(unsigned short u) {
    union { unsigned u; float f; } v; v.u = ((unsigned)u) << 16;
    return v.f;
}

static __device__ __forceinline__ void gload_lds16(const void* g, void* l) {
    __builtin_amdgcn_global_load_lds((const __attribute__((address_space(1))) void*)g,
                                     (__attribute__((address_space(3))) void*)l, 16, 0, 0);
}

static __device__ __forceinline__ int med3i(int a, int b, int c) {
    int r;
    asm("v_med3_i32 %0, %1, %2, %3" : "=v"(r) : "v"(a), "v"(b), "v"(c));
    return r;
}

// r11-proven top-3 insert (ternary max): a0>=a1>=a2 sorted invariant
#define T3R(d, a0, a1, a2) do { \
    int _n0 = ((d) > (a0)) ? (d) : (a0); \
    int _n1 = med3i((d), (a0), (a1)); \
    int _n2 = med3i((d), (a1), (a2)); \
    (a0) = _n0; (a1) = _n1; (a2) = _n2; } while (0)

#define T3R4(p, i) do { \
    T3R((p)[0], t0[i], t1[i], t2[i]); \
    T3R((p)[1], t0[i], t1[i], t2[i]); \
    T3R((p)[2], t0[i], t1[i], t2[i]); \
    T3R((p)[3], t0[i], t1[i], t2[i]); } while (0)

// float top-3 insert for the merge kernel
#define T3F(d, a0, a1, a2) do { \
    float _n0 = fmaxf((d), (a0)); \
    float _n1 = __builtin_amdgcn_fmed3f((d), (a0), (a1)); \
    float _n2 = __builtin_amdgcn_fmed3f((d), (a1), (a2)); \
    (a0) = _n0; (a1) = _n1; (a2) = _n2; } while (0)

// Kernel A: L2-normalize per (img,pos), quantize to i8 (scale 127, RNE).
__global__ __launch_bounds__(256) void dn4_normalize(const float* __restrict__ fm,
                                                     const int* __restrict__ elabel,
                                                     char* __restrict__ Qn,
                                                     char* __restrict__ Sn,
                                                     float* __restrict__ out) {
    int gid = blockIdx.x * blockDim.x + threadIdx.x;
    if (gid < 50) {   // label pass-through: out[250+gid]
        int bb = gid / 25, rem = gid % 25, wq = rem / 5, qi = rem % 5;
        out[250 + gid] = (float)elabel[(bb * NW + wq) * (NS + NQ) + NS + qi];
    }
    if (gid < 3960) { // zero S pad rows 2205..2303: 10 mats x 99 rows x 4 int4
        int mat = gid / 396, rem = gid % 396, rr = rem >> 2, k = rem & 3;
        int4v zv = {0, 0, 0, 0};
        *(int4v*)(Sn + (size_t)mat * (SROWS * FDIM) + (size_t)(NY + rr) * FDIM + k * 16) = zv;
    }
    if (gid >= NIMG * NPOS) return;
    int img = gid / NPOS;
    int pos = gid - img * NPOS;
    const float* src = fm + (size_t)img * IMG_ELEMS + pos;
    float v[FDIM];
    float ss = 0.f;
#pragma unroll
    for (int c = 0; c < FDIM; ++c) {
        float x = src[(size_t)c * NPOS];
        v[c] = x;
        ss += x * x;
    }
    float rn = 127.0f / (sqrtf(ss) + 1e-12f);
    int w[16];
#pragma unroll
    for (int k = 0; k < 16; ++k) {
        int q0 = __float2int_rn(v[4 * k]     * rn);
        int q1 = __float2int_rn(v[4 * k + 1] * rn);
        int q2 = __float2int_rn(v[4 * k + 2] * rn);
        int q3 = __float2int_rn(v[4 * k + 3] * rn);
        w[k] = (q0 & 0xff) | ((q1 & 0xff) << 8) | ((q2 & 0xff) << 16) | (q3 << 24);
    }
    char* dst;
    int i10 = img % 10;
    if (i10 < NS) {
        int bw = img / 10;
        dst = Sn + (size_t)bw * (SROWS * FDIM) + (size_t)(i10 * NPOS + pos) * FDIM;
    } else {
        int qidx = (img / 10) * NQ + (i10 - NS);
        dst = Qn + (size_t)qidx * (QROWS * FDIM) + (size_t)pos * FDIM;
    }
#pragma unroll
    for (int k = 0; k < 4; ++k) {
        int4v t = {w[4 * k], w[4 * k + 1], w[4 * k + 2], w[4 * k + 3]};
        *(int4v*)(dst + 16 * k) = t;
    }
}

// Kernel B: r12 geometry WITHOUT the spill. 3000 blocks = (bid, y-slice);
// 256 threads = 4 waves; wave owns 7 x-tiles (4*7 = 28). 12-tile LDS slice
// (12.3 KB). __launch_bounds__(256, 6): VGPR cap 85 >= ~75 live (r12's (256,8)
// forced a 64-reg cap -> scratch spill, WRITE 15.4 MB, and still ran 44 µs).
// 6 blocks/CU = 24 waves/CU: TLP hides the MFMA->T3R dependency latency that
// rounds 16-19 failed to hide via compiler-blocked ILP. Proven r11 inner loop.
__global__ __launch_bounds__(256, 6) void dn4_sim_mfma(const char* __restrict__ Qn,
                                                       const char* __restrict__ Sn,
                                                       unsigned short* __restrict__ gtop3) {
    __shared__ __align__(16) char stile[NT_S][TILE_B];   // 12,288 B

    // XCD swizzle (3000 % 8 == 0 -> simple bijective form)
    int orig = blockIdx.x;
    int unit = (orig & 7) * (NBLK_SIM / 8) + (orig >> 3);
    int bid = unit / NSLICE, ys = unit % NSLICE;

    int w = bid % NW;
    int q = (bid / NW) % (NW * NQ);
    int b = bid / (NW * NW * NQ);
    int wq = q / NQ, qi = q % NQ;
    int qidx = (b * NW + wq) * NQ + qi;

    const char* qbase = Qn + (size_t)qidx * (QROWS * FDIM);
    const char* sbase = Sn + (size_t)(b * NW + w) * (SROWS * FDIM);

    int t = threadIdx.x;
    int lane = t & 63, wv = t >> 6;
    int lo16 = lane & 15, hi4 = lane >> 4;

    // Stage source pre-swizzle: LDS linear [row][c] gets global [row][c ^ ((row>>1)&3)]
    int stg0 = ((lane >> 2) * FDIM) + ((((lane & 3) ^ ((lane >> 3) & 3)) << 4));
    int tbase = ys * NT_S;

    // Cooperative stage: 12 tiles over 4 waves, 1 gload_lds per tile
    for (int i = wv; i < NT_S; i += 4)
        gload_lds16(sbase + (size_t)(tbase + i) * TILE_B + stg0, &stile[i][0]);

    // B fragments (Q): 7 x-tiles; col = lo16 -> x = xt*16+lo16, k = hi4*16..+16
    int4v bq[7];
#pragma unroll
    for (int i = 0; i < 7; ++i) {
        int xt = wv * 7 + i;
        bq[i] = *(const int4v*)(qbase + (size_t)(xt * 16 + lo16) * FDIM + hi4 * 16);
    }

    asm volatile("s_waitcnt vmcnt(0)" ::: "memory");
    __syncthreads();   // the ONLY barrier

    int t0[7], t1[7], t2[7];
#pragma unroll
    for (int i = 0; i < 7; ++i) { t0[i] = INT_MIN; t1[i] = INT_MIN; t2[i] = INT_MIN; }

    int4v zc = {0, 0, 0, 0};

    // Swizzled read: row lo16, want col hi4 -> read hi4 ^ ((lo16>>1)&3)
    int rd = lo16 * FDIM + ((hi4 ^ ((lo16 >> 1) & 3)) << 4);

    int4v ca = *(const int4v*)(&stile[0][0] + rd);
    for (int tt = 0; tt < NT_S; ++tt) {
        int4v na = ca;
        if (tt + 1 < NT_S) na = *(const int4v*)(&stile[tt + 1][0] + rd);
        // 2-deep issue/consume stagger across the 7 x-tiles (r11/r12-proven)
        int4v pA = __builtin_amdgcn_mfma_i32_16x16x64_i8(ca, bq[0], zc, 0, 0, 0);
        int4v pB = __builtin_amdgcn_mfma_i32_16x16x64_i8(ca, bq[1], zc, 0, 0, 0);
        T3R4(pA, 0);
        int4v pC = __builtin_amdgcn_mfma_i32_16x16x64_i8(ca, bq[2], zc, 0, 0, 0);
        T3R4(pB, 1);
        int4v pD = __builtin_amdgcn_mfma_i32_16x16x64_i8(ca, bq[3], zc, 0, 0, 0);
        T3R4(pC, 2);
        int4v pE = __builtin_amdgcn_mfma_i32_16x16x64_i8(ca, bq[4], zc, 0, 0, 0);
        T3R4(pD, 3);
        int4v pF = __builtin_amdgcn_mfma_i32_16x16x64_i8(ca, bq[5], zc, 0, 0, 0);
        T3R4(pE, 4);
        int4v pG = __builtin_amdgcn_mfma_i32_16x16x64_i8(ca, bq[6], zc, 0, 0, 0);
        T3R4(pF, 5);
        T3R4(pG, 6);
        ca = na;
    }

    // Merge top-3 across the 4 y-quarter lane-groups (hi4), scale, write bf16
    const float INV = 1.0f / 16129.0f;   // 1/127^2
#pragma unroll
    for (int i = 0; i < 7; ++i) {
        int a0 = t0[i], a1 = t1[i], a2 = t2[i];
#pragma unroll
        for (int mk = 16; mk <= 32; mk <<= 1) {
            int c0 = __shfl_xor(a0, mk, 64);
            int c1 = __shfl_xor(a1, mk, 64);
            int c2 = __shfl_xor(a2, mk, 64);
            T3R(c0, a0, a1, a2);
            T3R(c1, a0, a1, a2);
            T3R(c2, a0, a1, a2);
        }
        if (hi4 == 0) {
            int x = (wv * 7 + i) * 16 + lo16;
            unsigned short* dst = gtop3 + ((size_t)(bid * QROWS + x) * NSLICE + ys) * 3;
            dst[0] = f2bf((float)a0 * INV);
            dst[1] = f2bf((float)a1 * INV);
            dst[2] = f2bf((float)a2 * INV);
        }
    }
}

// Kernel C: merge the 12 y-slices per (bid,x), sum top-3, block-reduce -> out[bid]
__global__ __launch_bounds__(448) void dn4_merge(const unsigned short* __restrict__ gtop3,
                                                 float* __restrict__ out) {
    __shared__ float red[7];
    int bid = blockIdx.x;
    int t = threadIdx.x, lane = t & 63, wv = t >> 6;
    // 36 bf16 per (bid,x) = 18 dwords (72 B stride, 4B aligned)
    const unsigned* p = (const unsigned*)(gtop3 + (size_t)(bid * QROWS + t) * (NSLICE * 3));
    float v[36];
#pragma unroll
    for (int j = 0; j < 18; ++j) {
        unsigned u = p[j];
        v[2 * j]     = bf2f((unsigned short)(u & 0xffffu));
        v[2 * j + 1] = bf2f((unsigned short)(u >> 16));
    }
    float a0 = v[0], a1 = v[1], a2 = v[2];
#pragma unroll
    for (int j = 3; j < 36; ++j) T3F(v[j], a0, a1, a2);
    float s = (t < NPOS) ? (a0 + a1 + a2) : 0.f;
#pragma unroll
    for (int off = 32; off >= 1; off >>= 1) s += __shfl_xor(s, off, 64);
    if (lane == 0) red[wv] = s;
    __syncthreads();
    if (t == 0) {
        float tot = 0.f;
#pragma unroll
        for (int i = 0; i < 7; ++i) tot += red[i];
        out[bid] = tot;
    }
}

extern "C" void kernel_launch(void* const* d_in, const int* in_sizes, int n_in,
                              void* d_out, int out_size, void* d_ws, size_t ws_size,
                              hipStream_t stream) {
    const float* fm     = (const float*)d_in[0];
    const int*   elabel = (const int*)d_in[1];
    float* out = (float*)d_out;

    char* Qn = (char*)d_ws;                                          // 50*448*64 i8  = 1.43 MB
    char* Sn = Qn + (size_t)NQIMG * QROWS * FDIM;                    // 10*2304*64 i8 = 1.47 MB
    unsigned short* gtop3 = (unsigned short*)(Sn + (size_t)10 * SROWS * FDIM);  // 250*448*36 ush = 8.06 MB

    int nthreads = NIMG * NPOS;
    dn4_normalize<<<(nthreads + 255) / 256, 256, 0, stream>>>(fm, elabel, Qn, Sn, out);
    dn4_sim_mfma<<<NBLK_SIM, 256, 0, stream>>>(Qn, Sn, gtop3);
    dn4_merge<<<NBLK, 448, 0, stream>>>(gtop3, out);
}

// Round 21
// 44.131 us; speedup vs baseline: 1.1669x; 1.1409x over previous
//
#include <hip/hip_runtime.h>
#include <hip/hip_bf16.h>
#include <math.h>
#include <limits.h>

// Problem constants (fixed by setup_inputs)
#define BS 2
#define NW 5
#define NS 5
#define NQ 5
#define FDIM 64
#define FH 21
#define FW 21
#define NPOS (FH*FW)            // 441
#define NIMG (BS*NW*(NS+NQ))    // 100
#define NQIMG 50
#define IMG_ELEMS (FDIM*NPOS)   // 28224
#define NY (NS*NPOS)            // 2205
#define QROWS 448               // 441 padded to 14*32
#define SROWS 2208              // 69 tiles of 32 rows; rows 2205..2207 zeroed
#define NSLICE 3                // y split: 69 = 3 * 23
#define NT_S 23                 // y-tiles (32 rows) per slice (46 KB LDS)
#define NBLK 250
#define NBLK_SIM (NBLK*NSLICE)  // 750
#define TILE_B 2048             // 32 rows x 64 B (i8) per tile

typedef __attribute__((ext_vector_type(4)))  int int4v;
typedef __attribute__((ext_vector_type(16))) int int16v;

static __device__ __forceinline__ unsigned short f2bf(float x) {
    union { float f; unsigned u; } v; v.f = x;
    unsigned r = v.u + 0x7fffu + ((v.u >> 16) & 1u);
    return (unsigned short)(r >> 16);
}

static __device__ __forceinline__ float bf2f(unsigned short u) {
    union { unsigned u; float f; } v; v.u = ((unsigned)u) << 16;
    return v.f;
}

static __device__ __forceinline__ void gload_lds16(const void* g, void* l) {
    __builtin_amdgcn_global_load_lds((const __attribute__((address_space(1))) void*)g,
                                     (__attribute__((address_space(3))) void*)l, 16, 0, 0);
}

static __device__ __forceinline__ int med3i(int a, int b, int c) {
    int r;
    asm("v_med3_i32 %0, %1, %2, %3" : "=v"(r) : "v"(a), "v"(b), "v"(c));
    return r;
}

// r11-proven top-3 insert (ternary max): a0>=a1>=a2 sorted invariant
#define T3R(d, a0, a1, a2) do { \
    int _n0 = ((d) > (a0)) ? (d) : (a0); \
    int _n1 = med3i((d), (a0), (a1)); \
    int _n2 = med3i((d), (a1), (a2)); \
    (a0) = _n0; (a1) = _n1; (a2) = _n2; } while (0)

// float top-3 insert for the merge kernel
#define T3F(d, a0, a1, a2) do { \
    float _n0 = fmaxf((d), (a0)); \
    float _n1 = __builtin_amdgcn_fmed3f((d), (a0), (a1)); \
    float _n2 = __builtin_amdgcn_fmed3f((d), (a1), (a2)); \
    (a0) = _n0; (a1) = _n1; (a2) = _n2; } while (0)

// Kernel A: L2-normalize per (img,pos), quantize to i8 (scale 127, RNE).
__global__ __launch_bounds__(256) void dn4_normalize(const float* __restrict__ fm,
                                                     const int* __restrict__ elabel,
                                                     char* __restrict__ Qn,
                                                     char* __restrict__ Sn,
                                                     float* __restrict__ out) {
    int gid = blockIdx.x * blockDim.x + threadIdx.x;
    if (gid < 50) {   // label pass-through: out[250+gid]
        int bb = gid / 25, rem = gid % 25, wq = rem / 5, qi = rem % 5;
        out[250 + gid] = (float)elabel[(bb * NW + wq) * (NS + NQ) + NS + qi];
    }
    if (gid < 120) {  // zero S pad rows 2205..2207: 10 mats x 3 rows x 4 int4
        int mat = gid / 12, rr = (gid % 12) >> 2, k = gid & 3;
        int4v zv = {0, 0, 0, 0};
        *(int4v*)(Sn + (size_t)mat * (SROWS * FDIM) + (size_t)(NY + rr) * FDIM + k * 16) = zv;
    }
    if (gid >= NIMG * NPOS) return;
    int img = gid / NPOS;
    int pos = gid - img * NPOS;
    const float* src = fm + (size_t)img * IMG_ELEMS + pos;
    float v[FDIM];
    float ss = 0.f;
#pragma unroll
    for (int c = 0; c < FDIM; ++c) {
        float x = src[(size_t)c * NPOS];
        v[c] = x;
        ss += x * x;
    }
    float rn = 127.0f / (sqrtf(ss) + 1e-12f);
    int w[16];
#pragma unroll
    for (int k = 0; k < 16; ++k) {
        int q0 = __float2int_rn(v[4 * k]     * rn);
        int q1 = __float2int_rn(v[4 * k + 1] * rn);
        int q2 = __float2int_rn(v[4 * k + 2] * rn);
        int q3 = __float2int_rn(v[4 * k + 3] * rn);
        w[k] = (q0 & 0xff) | ((q1 & 0xff) << 8) | ((q2 & 0xff) << 16) | (q3 << 24);
    }
    char* dst;
    int i10 = img % 10;
    if (i10 < NS) {
        int bw = img / 10;
        dst = Sn + (size_t)bw * (SROWS * FDIM) + (size_t)(i10 * NPOS + pos) * FDIM;
    } else {
        int qidx = (img / 10) * NQ + (i10 - NS);
        dst = Qn + (size_t)qidx * (QROWS * FDIM) + (size_t)pos * FDIM;
    }
#pragma unroll
    for (int k = 0; k < 4; ++k) {
        int4v t = {w[4 * k], w[4 * k + 1], w[4 * k + 2], w[4 * k + 3]};
        *(int4v*)(dst + 16 * k) = t;
    }
}

// Kernel B: 32x32x32 i8 MFMA. 750 blocks = (bid, y-slice of 23 32-row tiles);
// 448 threads = 7 waves; wave owns 2 x-tiles of 32. Per (x-tile, y-tile): TWO
// C-chained mfma_i32_32x32x32_i8 produce one 16-value D per lane (lane = one x,
// 16 y's) -> 4x fewer MFMA->VALU dependency-transition points and half the MFMA
// instructions vs 16x16x64 (the two levers that measurably moved the r11-r20
// wall). Top-3 = 3 regs/x-tile; cross-lane merge = single shfl_xor(32).
__global__ __launch_bounds__(448, 5) void dn4_sim_mfma(const char* __restrict__ Qn,
                                                       const char* __restrict__ Sn,
                                                       unsigned short* __restrict__ gtop3) {
    __shared__ __align__(16) char stile[NT_S][TILE_B];   // 47,104 B

    // m204 bijective chunked XCD swizzle over 750 units (750 = 8*93+6)
    int orig = blockIdx.x;
    int xcd = orig & 7, idx = orig >> 3;
    int unit = (xcd < 6 ? xcd * 94 : 6 * 94 + (xcd - 6) * 93) + idx;
    int bid = unit / NSLICE, ys = unit % NSLICE;

    int w = bid % NW;
    int q = (bid / NW) % (NW * NQ);
    int b = bid / (NW * NW * NQ);
    int wq = q / NQ, qi = q % NQ;
    int qidx = (b * NW + wq) * NQ + qi;

    const char* qbase = Qn + (size_t)qidx * (QROWS * FDIM);
    const char* sbase = Sn + (size_t)(b * NW + w) * (SROWS * FDIM);

    int t = threadIdx.x;
    int lane = t & 63, wv = t >> 6;
    int l5 = lane & 31, h = lane >> 5;

    // Stage source pre-swizzle: LDS linear [row][g] gets global [row][g ^ ((row>>1)&3)]
    // (g = 16B granule in a 64B row; verified full-32-bank spread per 8 rows)
    int stg0 = ((lane >> 2) * FDIM) + ((((lane & 3) ^ ((lane >> 3) & 3)) << 4));
    int tbase = ys * NT_S;

    // Cooperative stage: 23 tiles x 2 half-tiles over 7 waves
    for (int i = wv; i < 2 * NT_S; i += 7) {
        int tile = i >> 1, hh = i & 1;
        gload_lds16(sbase + (size_t)(tbase + tile) * TILE_B + hh * 1024 + stg0,
                    &stile[tile][hh * 1024]);
    }

    // B fragments (Q): col = l5 -> x = xt*32+l5, k-bytes = kh*32 + h*16 .. +16
    int4v bq[2][2];
#pragma unroll
    for (int j = 0; j < 2; ++j) {
        int x = (wv * 2 + j) * 32 + l5;
        const char* qp = qbase + (size_t)x * FDIM + h * 16;
        bq[j][0] = *(const int4v*)(qp);
        bq[j][1] = *(const int4v*)(qp + 32);
    }

    asm volatile("s_waitcnt vmcnt(0)" ::: "memory");
    __syncthreads();   // the ONLY barrier

    int t0[2], t1[2], t2[2];
#pragma unroll
    for (int j = 0; j < 2; ++j) { t0[j] = INT_MIN; t1[j] = INT_MIN; t2[j] = INT_MIN; }

    int16v zc = {0,0,0,0, 0,0,0,0, 0,0,0,0, 0,0,0,0};

    // A reads (S): row = l5, k-half kh, granule gk = kh*2+h, swizzled ^= (row>>1)&3
    int rd0 = l5 * FDIM + (((0 + h) ^ ((l5 >> 1) & 3)) << 4);   // kh=0
    int rd1 = l5 * FDIM + (((2 + h) ^ ((l5 >> 1) & 3)) << 4);   // kh=1

    int4v a0 = *(const int4v*)(&stile[0][0] + rd0);
    int4v a1 = *(const int4v*)(&stile[0][0] + rd1);
    for (int tt = 0; tt < NT_S; ++tt) {
        int4v na0 = a0, na1 = a1;
        if (tt + 1 < NT_S) {
            na0 = *(const int4v*)(&stile[tt + 1][0] + rd0);
            na1 = *(const int4v*)(&stile[tt + 1][0] + rd1);
        }
        // two x-tiles, each = 2 C-chained K=32 MFMAs -> one 16-value D
        int16v dA = __builtin_amdgcn_mfma_i32_32x32x32_i8(a0, bq[0][0], zc, 0, 0, 0);
        dA = __builtin_amdgcn_mfma_i32_32x32x32_i8(a1, bq[0][1], dA, 0, 0, 0);
        int16v dB = __builtin_amdgcn_mfma_i32_32x32x32_i8(a0, bq[1][0], zc, 0, 0, 0);
        dB = __builtin_amdgcn_mfma_i32_32x32x32_i8(a1, bq[1][1], dB, 0, 0, 0);
        // 32 T3R (two independent banks interleaved)
#pragma unroll
        for (int r = 0; r < 16; ++r) {
            T3R(dA[r], t0[0], t1[0], t2[0]);
            T3R(dB[r], t0[1], t1[1], t2[1]);
        }
        a0 = na0; a1 = na1;
    }

    // Merge across lane^32 (same x, other 16 y's), scale, write bf16
    const float INV = 1.0f / 16129.0f;   // 1/127^2
#pragma unroll
    for (int j = 0; j < 2; ++j) {
        int a0_ = t0[j], a1_ = t1[j], a2_ = t2[j];
        int c0 = __shfl_xor(a0_, 32, 64);
        int c1 = __shfl_xor(a1_, 32, 64);
        int c2 = __shfl_xor(a2_, 32, 64);
        T3R(c0, a0_, a1_, a2_);
        T3R(c1, a0_, a1_, a2_);
        T3R(c2, a0_, a1_, a2_);
        if (h == 0) {
            int x = (wv * 2 + j) * 32 + l5;
            unsigned short* dst = gtop3 + ((size_t)(bid * QROWS + x) * NSLICE + ys) * 3;
            dst[0] = f2bf((float)a0_ * INV);
            dst[1] = f2bf((float)a1_ * INV);
            dst[2] = f2bf((float)a2_ * INV);
        }
    }
}

// Kernel C: merge the 3 y-slices per (bid,x), sum top-3, block-reduce -> out[bid]
__global__ __launch_bounds__(448) void dn4_merge(const unsigned short* __restrict__ gtop3,
                                                 float* __restrict__ out) {
    __shared__ float red[7];
    int bid = blockIdx.x;
    int t = threadIdx.x, lane = t & 63, wv = t >> 6;
    const unsigned short* p = gtop3 + (size_t)(bid * QROWS + t) * (NSLICE * 3);
    float v[9];
#pragma unroll
    for (int j = 0; j < 9; ++j) v[j] = bf2f(p[j]);
    float a0 = v[0], a1 = v[1], a2 = v[2];
#pragma unroll
    for (int j = 3; j < 9; ++j) T3F(v[j], a0, a1, a2);
    float s = (t < NPOS) ? (a0 + a1 + a2) : 0.f;
#pragma unroll
    for (int off = 32; off >= 1; off >>= 1) s += __shfl_xor(s, off, 64);
    if (lane == 0) red[wv] = s;
    __syncthreads();
    if (t == 0) {
        float tot = 0.f;
#pragma unroll
        for (int i = 0; i < 7; ++i) tot += red[i];
        out[bid] = tot;
    }
}

extern "C" void kernel_launch(void* const* d_in, const int* in_sizes, int n_in,
                              void* d_out, int out_size, void* d_ws, size_t ws_size,
                              hipStream_t stream) {
    const float* fm     = (const float*)d_in[0];
    const int*   elabel = (const int*)d_in[1];
    float* out = (float*)d_out;

    char* Qn = (char*)d_ws;                                   // 50*448*64 i8  = 1.43 MB
    char* Sn = Qn + (size_t)NQIMG * QROWS * FDIM;             // 10*2208*64 i8 = 1.41 MB
    unsigned short* gtop3 = (unsigned short*)(Sn + (size_t)10 * SROWS * FDIM);  // 250*448*9 ush = 2.02 MB

    int nthreads = NIMG * NPOS;
    dn4_normalize<<<(nthreads + 255) / 256, 256, 0, stream>>>(fm, elabel, Qn, Sn, out);
    dn4_sim_mfma<<<NBLK_SIM, 448, 0, stream>>>(Qn, Sn, gtop3);
    dn4_merge<<<NBLK, 448, 0, stream>>>(gtop3, out);
}